// Round 10
// baseline (391.657 us; speedup 1.0000x reference)
//
#include <hip/hip_runtime.h>
#include <math.h>

#define TW 44            // tile width & LDS stride (44x44 tile)
#define SW 40            // Rws/S2 stride
#define FINF 3.4e38f

__device__ __forceinline__ int iclip(int v, int hi) {
  return v < 0 ? 0 : (v > hi ? hi : v);
}

// Exact f32 values of the reference D8 (computed in f64, cast to f32).
constexpr float CA = 0.35355339059327373f;
constexpr float K1 = 0.49039264020161522f;
constexpr float K2 = 0.46193976625564337f;
constexpr float K3 = 0.41573480615127262f;
constexpr float K4 = 0.35355339059327379f;
constexpr float K5 = 0.27778511650980111f;
constexpr float K6 = 0.19134171618254489f;
constexpr float K7 = 0.097545161008064135f;

constexpr float DCT8[8][8] = {
  { CA, CA, CA, CA, CA, CA, CA, CA},
  { K1, K3, K5, K7,-K7,-K5,-K3,-K1},
  { K2, K6,-K6,-K2,-K2,-K6, K6, K2},
  { K3,-K7,-K1,-K5, K5, K1, K7,-K3},
  { K4,-K4,-K4, K4, K4,-K4,-K4, K4},
  { K5,-K1, K7, K3,-K3,-K7, K1,-K5},
  { K6,-K2, K2,-K6,-K6, K2,-K2, K6},
  { K7,-K5, K3,-K1, K1,-K3, K5,-K7},
};

// lane-xor exchange: DPP for 1/2/8, ds_swizzle for 4/16, shfl for 32
__device__ __forceinline__ int sxor_i(int v, int m) {
  switch (m) {
    case 1:  return __builtin_amdgcn_update_dpp(0, v, 0xB1, 0xF, 0xF, true);
    case 2:  return __builtin_amdgcn_update_dpp(0, v, 0x4E, 0xF, 0xF, true);
    case 4:  return __builtin_amdgcn_ds_swizzle(v, (4 << 10) | 0x1F);
    case 8:  return __builtin_amdgcn_update_dpp(0, v, 0x128, 0xF, 0xF, true); // row_ror:8
    case 16: return __builtin_amdgcn_ds_swizzle(v, (16 << 10) | 0x1F);
    default: return __shfl_xor(v, 32, 64);
  }
}
__device__ __forceinline__ float sxor_f(float v, int m) {
  return __int_as_float(sxor_i(__float_as_int(v), m));
}

// broadcast from quad lane s (VALU DPP)
__device__ __forceinline__ float qbcast(float v, int s) {
  int x = __float_as_int(v), r;
  switch (s) {
    case 0:  r = __builtin_amdgcn_update_dpp(0, x, 0x00, 0xF, 0xF, true); break;
    case 1:  r = __builtin_amdgcn_update_dpp(0, x, 0x55, 0xF, 0xF, true); break;
    case 2:  r = __builtin_amdgcn_update_dpp(0, x, 0xAA, 0xF, 0xF, true); break;
    default: r = __builtin_amdgcn_update_dpp(0, x, 0xFF, 0xF, 0xF, true); break;
  }
  return __int_as_float(r);
}

// forward: row DCT (lane-local literals) then column DCT (quad mix)
__device__ __forceinline__ void fwd_rowcol(float X[2][8], float U[2][8],
                                           const float Ca0[8], const float Ca1[8]) {
#pragma unroll
  for (int r = 0; r < 2; r++)
#pragma unroll
    for (int d = 0; d < 8; d++) {
      float s = X[r][0] * DCT8[d][0];
#pragma unroll
      for (int c = 1; c < 8; c++) s += X[r][c] * DCT8[d][c];
      U[r][d] = s;
    }
#pragma unroll
  for (int r = 0; r < 2; r++)
#pragma unroll
    for (int d = 0; d < 8; d++) X[r][d] = 0.f;
#pragma unroll
  for (int b = 0; b < 8; b++)
#pragma unroll
    for (int d = 0; d < 8; d++) {
      float yb = qbcast(U[b & 1][d], b >> 1);
      X[0][d] += Ca0[b] * yb;
      X[1][d] += Ca1[b] * yb;
    }
}

// inverse: column (quad mix, D^T coeffs) then row (lane-local literals)
__device__ __forceinline__ void inv_colrow(float X[2][8], float U[2][8],
                                           const float Ct0[8], const float Ct1[8]) {
#pragma unroll
  for (int r = 0; r < 2; r++)
#pragma unroll
    for (int d = 0; d < 8; d++) U[r][d] = 0.f;
#pragma unroll
  for (int a = 0; a < 8; a++)
#pragma unroll
    for (int d = 0; d < 8; d++) {
      float za = qbcast(X[a & 1][d], a >> 1);
      U[0][d] += Ct0[a] * za;
      U[1][d] += Ct1[a] * za;
    }
#pragma unroll
  for (int r = 0; r < 2; r++)
#pragma unroll
    for (int c = 0; c < 8; c++) {
      float s = U[r][0] * DCT8[0][c];
#pragma unroll
      for (int d = 1; d < 8; d++) s += U[r][d] * DCT8[d][c];
      X[r][c] = s;
    }
}

// 16-point Walsh-Hadamard across lane bits 2..5, scale 1/4
__device__ __forceinline__ void had16r(float X[2][8], int lane) {
#pragma unroll
  for (int m = 4; m <= 32; m <<= 1) {
    bool hi = (lane & m) != 0;
#pragma unroll
    for (int r = 0; r < 2; r++)
#pragma unroll
      for (int d = 0; d < 8; d++) {
        float tv = sxor_f(X[r][d], m);
        X[r][d] = hi ? (tv - X[r][d]) : (X[r][d] + tv);
      }
  }
#pragma unroll
  for (int r = 0; r < 2; r++)
#pragma unroll
    for (int d = 0; d < 8; d++) X[r][d] *= 0.25f;
}

template <int WIEN>
__global__ __launch_bounds__(256, 4) void bm3d_pass(
    const int* __restrict__ img, const float* __restrict__ basic,
    const int* __restrict__ pvar,
    float* __restrict__ num, float* __restrict__ den) {
  __shared__ float ldsD[64], ldsDT[64];
  __shared__ __align__(16) float wdist[4][84];
  __shared__ int wsel[4][16];
  __shared__ float S2[37 * SW];
  __shared__ float tileS[44 * TW];
  __shared__ float tileN[WIEN ? 44 * TW : 1];
  __shared__ float accN[44 * TW];   // Rws overlays here during box-sum phase
  __shared__ float accD[44 * TW];

  int t = threadIdx.x;
  int brow = blockIdx.x / 24, bcol = blockIdx.x - brow * 24;
  int bi0 = brow * 16 - 12; int bi = bi0 < 0 ? 0 : (bi0 > 340 ? 340 : bi0);
  int ub0 = bcol * 16 - 12; int ub = ub0 < 0 ? 0 : (ub0 > 340 ? 340 : ub0);

  if (t < 64) ldsD[t] = DCT8[t >> 3][t & 7];
  else if (t < 128) { int u = t - 64; ldsDT[u] = DCT8[u & 7][u >> 3]; }

  // ---- tile load: 44 rows x 11 float4; fully in-bounds by construction ----
  for (int e4 = t; e4 < 484; e4 += 256) {
    int r = e4 / 11, c4 = (e4 - r * 11) << 2;
    int gidx = (bi + r) * 384 + ub + c4;
    int o = r * TW + c4;
    int4 iv = *(const int4*)&img[gidx];
    float4 fv = make_float4((float)iv.x, (float)iv.y, (float)iv.z, (float)iv.w);
    if (WIEN) {
      *(float4*)&tileS[o] = *(const float4*)&basic[gidx];
      *(float4*)&tileN[o] = fv;
    } else {
      *(float4*)&tileS[o] = fv;
    }
  }
  __syncthreads();

  // ---- box sums of squared tileS (Rws in accN space, then S2) ----
  float* Rws = accN;
  for (int e = t; e < 44 * 37; e += 256) {
    int r = e / 37, j = e - r * 37;
    const float* p = tileS + r * TW + j;
    float s = 0.f;
#pragma unroll
    for (int d = 0; d < 8; d++) { float v = p[d]; s += v * v; }
    Rws[r * SW + j] = s;
  }
  __syncthreads();
  for (int e = t; e < 37 * 37; e += 256) {
    int i = e / 37, j = e - i * 37;
    float s = 0.f;
#pragma unroll
    for (int d = 0; d < 8; d++) s += Rws[(i + d) * SW + j];
    S2[i * SW + j] = s;
  }
  __syncthreads();
  for (int e = t; e < 44 * TW; e += 256) { accN[e] = 0.f; accD[e] = 0.f; }
  __syncthreads();

  float sigma2 = (float)pvar[0];
  int wv = t >> 6, lane = t & 63;
  int rc = bcol * 4 + wv;
  bool colAct = rc < 95;
  int rj = (colAct ? rc : 94) * 4;
  int roj = rj - ub;
  int cB = lane < 17 ? 64 + lane : 80;
  int ajA = iclip(rj + (lane % 9) * 3 - 12, 376) - ub;
  int ajB = iclip(rj + (cB % 9) * 3 - 12, 376) - ub;
  int k = lane >> 2, q = lane & 3;
  const float* tileNN = WIEN ? tileN : tileS;

  for (int it = 0; it < 4; it++) {
    int rr = brow * 4 + it;
    if (!(colAct && rr < 95)) continue;     // wave-uniform guard
    int ri = rr * 4;
    int roi = ri - bi;
    int aiA = iclip(ri + (lane / 9) * 3 - 12, 376) - bi;
    int aiB = iclip(ri + (cB / 9) * 3 - 12, 376) - bi;

    // ---- match: scr only (scc/srr from S2) ----
    float scrA = 0.f, scrB = 0.f;
#pragma unroll
    for (int i = 0; i < 8; i++) {
      float4 ra = *(const float4*)(tileS + (roi + i) * TW + roj);   // roj % 4 == 0
      float4 rb = *(const float4*)(tileS + (roi + i) * TW + roj + 4);
      float rv[8] = {ra.x, ra.y, ra.z, ra.w, rb.x, rb.y, rb.z, rb.w};
      const float* ap = tileS + (aiA + i) * TW + ajA;
      const float* bp = tileS + (aiB + i) * TW + ajB;
#pragma unroll
      for (int j = 0; j < 8; j++) {
        scrA += ap[j] * rv[j];
        scrB += bp[j] * rv[j];
      }
    }
    float srr = S2[roi * SW + roj];
    float dA = fmaf(-2.f, scrA, S2[aiA * SW + ajA]) + srr;
    float dB = lane < 17 ? fmaf(-2.f, scrB, S2[aiB * SW + ajB]) + srr : FINF;

    wdist[wv][lane] = dA;
    if (lane < 17)      wdist[wv][64 + lane] = dB;
    else if (lane < 20) wdist[wv][64 + lane] = FINF;

    // ---- rank-count top-16 (lexicographic (d, idx) = lax.top_k order) ----
    int rA = 0, rB = 0;
    const float4* wp = (const float4*)&wdist[wv][0];
    int idxB = 64 + lane;
#pragma unroll 3
    for (int c4 = 0; c4 < 21; c4++) {
      float4 v = wp[c4];
      float ev[4] = {v.x, v.y, v.z, v.w};
#pragma unroll
      for (int u = 0; u < 4; u++) {
        int c2 = c4 * 4 + u;
        rA += (ev[u] < dA || (ev[u] == dA && c2 < lane)) ? 1 : 0;
        rB += (ev[u] < dB || (ev[u] == dB && c2 < idxB)) ? 1 : 0;
      }
    }
    if (rA < 16) wsel[wv][rA] = (aiA << 8) | ajA;
    if (lane < 17 && rB < 16) wsel[wv][rB] = (aiB << 8) | ajB;

    // ---- per-lane geometry + coefficients ----
    int sp = wsel[wv][k];
    int gi0 = (sp >> 8) + 2 * q, gj0 = sp & 255;

    float Ca0[8], Ca1[8];
    *(float4*)&Ca0[0] = *(const float4*)&ldsD[(2 * q) * 8];
    *(float4*)&Ca0[4] = *(const float4*)&ldsD[(2 * q) * 8 + 4];
    *(float4*)&Ca1[0] = *(const float4*)&ldsD[(2 * q + 1) * 8];
    *(float4*)&Ca1[4] = *(const float4*)&ldsD[(2 * q + 1) * 8 + 4];

    float X[2][8], U[2][8];
    float w;

    if (WIEN) {
      float Z[2][8];
#pragma unroll
      for (int r = 0; r < 2; r++)
#pragma unroll
        for (int c = 0; c < 8; c++) Z[r][c] = tileS[(gi0 + r) * TW + gj0 + c];
      fwd_rowcol(Z, U, Ca0, Ca1);
      had16r(Z, lane);                        // cb

#pragma unroll
      for (int r = 0; r < 2; r++)
#pragma unroll
        for (int c = 0; c < 8; c++) X[r][c] = tileNN[(gi0 + r) * TW + gj0 + c];
      fwd_rowcol(X, U, Ca0, Ca1);
      had16r(X, lane);                        // cn

      float p = 0.f;
#pragma unroll
      for (int r = 0; r < 2; r++)
#pragma unroll
        for (int d = 0; d < 8; d++) {
          float cb = Z[r][d];
          float we = cb * cb / (cb * cb + sigma2);
          X[r][d] = we * X[r][d];
          p += we * we;
        }
#pragma unroll
      for (int m = 1; m <= 32; m <<= 1) p += sxor_f(p, m);
      w = 1.f / (sigma2 * fmaxf(p, 1e-8f));
    } else {
#pragma unroll
      for (int r = 0; r < 2; r++)
#pragma unroll
        for (int c = 0; c < 8; c++) X[r][c] = tileNN[(gi0 + r) * TW + gj0 + c];
      fwd_rowcol(X, U, Ca0, Ca1);
      had16r(X, lane);

      float thr = 2.7f * sqrtf(sigma2);
      int cnt = 0;
#pragma unroll
      for (int r = 0; r < 2; r++)
#pragma unroll
        for (int d = 0; d < 8; d++) {
          bool keep = (fabsf(X[r][d]) > thr) || (lane == 0 && r == 0 && d == 0);
          cnt += (int)__popcll(__ballot(keep));
          if (!keep) X[r][d] = 0.f;
        }
      w = 1.f / (sigma2 * fmaxf((float)cnt, 1.f));
    }

    had16r(X, lane);
    float Ct0[8], Ct1[8];
#pragma unroll
    for (int a = 0; a < 8; a++) {      // D^T rows for this lane's two b's
      Ct0[a] = ldsDT[(2 * q) * 8 + a];
      Ct1[a] = ldsDT[(2 * q + 1) * 8 + a];
    }
    inv_colrow(X, U, Ct0, Ct1);

    // ---- accumulate into block-shared num/den tiles ----
#pragma unroll
    for (int r = 0; r < 2; r++)
#pragma unroll
      for (int c = 0; c < 8; c++) {
        int off = (gi0 + r) * TW + gj0 + c;
        atomicAdd(&accN[off], w * X[r][c]);
        atomicAdd(&accD[off], w);
      }
  }

  // ---- single flush for all 16 groups ----
  __syncthreads();
  for (int e = t; e < 44 * TW; e += 256) {
    float dv = accD[e];
    if (dv != 0.f) {
      int r = e / TW, c = e - r * TW;
      int gp = (bi + r) * 384 + ub + c;
      atomicAdd(&num[gp], accN[e]);
      atomicAdd(&den[gp], dv);
    }
  }
}

__global__ void div_kernel(const float* __restrict__ num,
                           const float* __restrict__ den,
                           float* __restrict__ out, int npix) {
  int i = blockIdx.x * blockDim.x + threadIdx.x;
  if (i < npix) out[i] = num[i] / fmaxf(den[i], 1e-8f);
}

extern "C" void kernel_launch(void* const* d_in, const int* in_sizes, int n_in,
                              void* d_out, int out_size, void* d_ws, size_t ws_size,
                              hipStream_t stream) {
  const int* img  = (const int*)d_in[0];
  const int* pvar = (const int*)d_in[1];
  float* out = (float*)d_out;
  float* ws  = (float*)d_ws;

  const int NPIX = 384 * 384;
  float* num1  = ws + 0 * NPIX;
  float* den1  = ws + 1 * NPIX;
  float* basic = ws + 2 * NPIX;
  float* num2  = ws + 3 * NPIX;
  float* den2  = ws + 4 * NPIX;

  hipMemsetAsync(num1, 0, (size_t)2 * NPIX * sizeof(float), stream);
  hipMemsetAsync(num2, 0, (size_t)2 * NPIX * sizeof(float), stream);

  const int NBLK = 24 * 24;   // 24 row-blocks x 24 col-blocks, 16 groups each
  bm3d_pass<0><<<NBLK, 256, 0, stream>>>(img, nullptr, pvar, num1, den1);
  div_kernel<<<(NPIX + 255) / 256, 256, 0, stream>>>(num1, den1, basic, NPIX);
  bm3d_pass<1><<<NBLK, 256, 0, stream>>>(img, basic, pvar, num2, den2);
  div_kernel<<<(NPIX + 255) / 256, 256, 0, stream>>>(num2, den2, out, NPIX);
}

// Round 11
// 276.887 us; speedup vs baseline: 1.4145x; 1.4145x over previous
//
#include <hip/hip_runtime.h>
#include <math.h>

#define TS 45            // LDS tile stride (32 rows x 44 used cols, +1 pad)
#define FINF 3.4e38f

__device__ __forceinline__ int iclip(int v, int hi) {
  return v < 0 ? 0 : (v > hi ? hi : v);
}

// Exact f32 values of the reference D8 (computed in f64, cast to f32).
constexpr float CA = 0.35355339059327373f;
constexpr float K1 = 0.49039264020161522f;
constexpr float K2 = 0.46193976625564337f;
constexpr float K3 = 0.41573480615127262f;
constexpr float K4 = 0.35355339059327379f;
constexpr float K5 = 0.27778511650980111f;
constexpr float K6 = 0.19134171618254489f;
constexpr float K7 = 0.097545161008064135f;

constexpr float DCT8[8][8] = {
  { CA, CA, CA, CA, CA, CA, CA, CA},
  { K1, K3, K5, K7,-K7,-K5,-K3,-K1},
  { K2, K6,-K6,-K2,-K2,-K6, K6, K2},
  { K3,-K7,-K1,-K5, K5, K1, K7,-K3},
  { K4,-K4,-K4, K4, K4,-K4,-K4, K4},
  { K5,-K1, K7, K3,-K3,-K7, K1,-K5},
  { K6,-K2, K2,-K6,-K6, K2,-K2, K6},
  { K7,-K5, K3,-K1, K1,-K3, K5,-K7},
};

// lane-xor exchange: DPP for 1/2, ds_swizzle for 4/8/16, shfl for 32
__device__ __forceinline__ int sxor_i(int v, int m) {
  switch (m) {
    case 1:  return __builtin_amdgcn_update_dpp(0, v, 0xB1, 0xF, 0xF, true); // quad_perm [1,0,3,2]
    case 2:  return __builtin_amdgcn_update_dpp(0, v, 0x4E, 0xF, 0xF, true); // quad_perm [2,3,0,1]
    case 4:  return __builtin_amdgcn_ds_swizzle(v, (4 << 10) | 0x1F);
    case 8:  return __builtin_amdgcn_ds_swizzle(v, (8 << 10) | 0x1F);
    case 16: return __builtin_amdgcn_ds_swizzle(v, (16 << 10) | 0x1F);
    default: return __shfl_xor(v, 32, 64);
  }
}
__device__ __forceinline__ float sxor_f(float v, int m) {
  return __int_as_float(sxor_i(__float_as_int(v), m));
}

// broadcast from quad lane s (VALU DPP, no LDS pipe)
__device__ __forceinline__ float qbcast(float v, int s) {
  int x = __float_as_int(v), r;
  switch (s) {
    case 0:  r = __builtin_amdgcn_update_dpp(0, x, 0x00, 0xF, 0xF, true); break;
    case 1:  r = __builtin_amdgcn_update_dpp(0, x, 0x55, 0xF, 0xF, true); break;
    case 2:  r = __builtin_amdgcn_update_dpp(0, x, 0xAA, 0xF, 0xF, true); break;
    default: r = __builtin_amdgcn_update_dpp(0, x, 0xFF, 0xF, 0xF, true); break;
  }
  return __int_as_float(r);
}

// forward: row DCT (lane-local, literal coeffs) then column DCT (quad mix)
__device__ __forceinline__ void fwd_rowcol(float X[2][8], float U[2][8],
                                           const float Ca0[8], const float Ca1[8]) {
#pragma unroll
  for (int r = 0; r < 2; r++)
#pragma unroll
    for (int d = 0; d < 8; d++) {
      float s = X[r][0] * DCT8[d][0];
#pragma unroll
      for (int c = 1; c < 8; c++) s += X[r][c] * DCT8[d][c];
      U[r][d] = s;
    }
#pragma unroll
  for (int r = 0; r < 2; r++)
#pragma unroll
    for (int d = 0; d < 8; d++) X[r][d] = 0.f;
#pragma unroll
  for (int b = 0; b < 8; b++)
#pragma unroll
    for (int d = 0; d < 8; d++) {
      float yb = qbcast(U[b & 1][d], b >> 1);
      X[0][d] += Ca0[b] * yb;
      X[1][d] += Ca1[b] * yb;
    }
}

// inverse: column (quad mix, D^T coeffs) then row (lane-local literals)
__device__ __forceinline__ void inv_colrow(float X[2][8], float U[2][8],
                                           const float Ct0[8], const float Ct1[8]) {
#pragma unroll
  for (int r = 0; r < 2; r++)
#pragma unroll
    for (int d = 0; d < 8; d++) U[r][d] = 0.f;
#pragma unroll
  for (int a = 0; a < 8; a++)
#pragma unroll
    for (int d = 0; d < 8; d++) {
      float za = qbcast(X[a & 1][d], a >> 1);
      U[0][d] += Ct0[a] * za;
      U[1][d] += Ct1[a] * za;
    }
#pragma unroll
  for (int r = 0; r < 2; r++)
#pragma unroll
    for (int c = 0; c < 8; c++) {
      float s = U[r][0] * DCT8[0][c];
#pragma unroll
      for (int d = 1; d < 8; d++) s += U[r][d] * DCT8[d][c];
      X[r][c] = s;
    }
}

// 16-point Walsh-Hadamard across lane bits 2..5 (k dim), scale 1/4
__device__ __forceinline__ void had16r(float X[2][8], int lane) {
#pragma unroll
  for (int m = 4; m <= 32; m <<= 1) {
    bool hi = (lane & m) != 0;
#pragma unroll
    for (int r = 0; r < 2; r++)
#pragma unroll
      for (int d = 0; d < 8; d++) {
        float tv = sxor_f(X[r][d], m);
        X[r][d] = hi ? (tv - X[r][d]) : (X[r][d] + tv);
      }
  }
#pragma unroll
  for (int r = 0; r < 2; r++)
#pragma unroll
    for (int d = 0; d < 8; d++) X[r][d] *= 0.25f;
}

template <int WIEN>
__device__ __forceinline__ void group_worker(
    const float* __restrict__ tileS, const float* __restrict__ tileN,
    float* __restrict__ accN, float* __restrict__ accD,
    const float* __restrict__ ldsD, int* __restrict__ sel,
    float* __restrict__ wdrow,
    int lane, int ri, int rj, int bi, int ub, float sigma2) {

  // ---------- block match: 81 candidates, lane holds cand lane and 64+lane ----
  int cB = lane < 17 ? 64 + lane : 80;
  int aiA = iclip(ri + (lane / 9) * 3 - 12, 376) - bi;
  int ajA = iclip(rj + (lane % 9) * 3 - 12, 376) - ub;
  int aiB = iclip(ri + (cB / 9) * 3 - 12, 376) - bi;
  int ajB = iclip(rj + (cB % 9) * 3 - 12, 376) - ub;
  int roi = ri - bi, roj = rj - ub;
  float sccA = 0.f, scrA = 0.f, sccB = 0.f, scrB = 0.f, srr = 0.f;
#pragma unroll
  for (int i = 0; i < 8; i++) {
    const float* rr = tileS + (roi + i) * TS + roj;
    const float* ar = tileS + (aiA + i) * TS + ajA;
    const float* br = tileS + (aiB + i) * TS + ajB;
#pragma unroll
    for (int j = 0; j < 8; j++) {
      float rv = rr[j], av = ar[j], bv = br[j];
      sccA += av * av; scrA += av * rv;
      sccB += bv * bv; scrB += bv * rv;
      srr  += rv * rv;
    }
  }
  float d0 = sccA - 2.f * scrA + srr;
  float d1 = lane < 17 ? (sccB - 2.f * scrB + srr) : FINF;

  // ---------- rank-count top-16 (lexicographic (d, idx) = lax.top_k order) ----
  // per-wave dist table; same-wave LDS RAW (compiler inserts lgkm waits)
  wdrow[lane] = d0;
  if (lane < 17)      wdrow[64 + lane] = d1;
  else if (lane < 20) wdrow[64 + lane] = FINF;

  int rank0 = 0, rank1 = 0;
  const float4* wp = (const float4*)wdrow;
  int idxB = 64 + lane;
#pragma unroll 3
  for (int c4 = 0; c4 < 21; c4++) {
    float4 v = wp[c4];
    float ev[4] = {v.x, v.y, v.z, v.w};
#pragma unroll
    for (int u = 0; u < 4; u++) {
      int c2 = c4 * 4 + u;
      rank0 += (ev[u] < d0 || (ev[u] == d0 && c2 < lane)) ? 1 : 0;
      rank1 += (ev[u] < d1 || (ev[u] == d1 && c2 < idxB)) ? 1 : 0;
    }
  }
  if (rank0 < 16) sel[rank0] = (aiA << 8) | ajA;
  if (lane < 17 && rank1 < 16) sel[rank1] = (aiB << 8) | ajB;

  // ---------- per-lane geometry + column-DCT coefficient rows ---------------
  int q = lane & 3, k = lane >> 2;
  float Ca0[8], Ca1[8];
#pragma unroll
  for (int b = 0; b < 8; b++) {
    Ca0[b] = ldsD[(2 * q) * 8 + b];
    Ca1[b] = ldsD[(2 * q + 1) * 8 + b];
  }
  int sp = sel[k];
  int gi = (sp >> 8) + 2 * q, gj = sp & 255;

  float X[2][8], U[2][8], ZB[2][8];
  float w;

  if (WIEN) {                      // cb = fwd3d(basic group)
#pragma unroll
    for (int r = 0; r < 2; r++)
#pragma unroll
      for (int c = 0; c < 8; c++) ZB[r][c] = tileS[(gi + r) * TS + gj + c];
    fwd_rowcol(ZB, U, Ca0, Ca1);
    had16r(ZB, lane);
  }

  // cn / noisy group
#pragma unroll
  for (int r = 0; r < 2; r++)
#pragma unroll
    for (int c = 0; c < 8; c++) X[r][c] = tileN[(gi + r) * TS + gj + c];
  fwd_rowcol(X, U, Ca0, Ca1);
  had16r(X, lane);

  if (WIEN) {
    float part = 0.f;
#pragma unroll
    for (int r = 0; r < 2; r++)
#pragma unroll
      for (int d = 0; d < 8; d++) {
        float cb = ZB[r][d];
        float we = cb * cb / (cb * cb + sigma2);
        X[r][d] = we * X[r][d];
        part += we * we;
      }
#pragma unroll
    for (int m = 1; m <= 32; m <<= 1) part += sxor_f(part, m);
    w = 1.f / (sigma2 * fmaxf(part, 1e-8f));
  } else {
    float thr = 2.7f * sqrtf(sigma2);
    int cnt = 0;
#pragma unroll
    for (int r = 0; r < 2; r++)
#pragma unroll
      for (int d = 0; d < 8; d++) {
        bool keep = (fabsf(X[r][d]) > thr) || (lane == 0 && r == 0 && d == 0);
        cnt += (int)__popcll(__ballot(keep));
        if (!keep) X[r][d] = 0.f;
      }
    w = 1.f / (sigma2 * fmaxf((float)cnt, 1.f));
  }

  // ---------- inverse 3D transform ------------------------------------------
  had16r(X, lane);
#pragma unroll
  for (int a = 0; a < 8; a++) {    // D^T rows for this lane's two b's
    Ca0[a] = ldsD[a * 8 + 2 * q];
    Ca1[a] = ldsD[a * 8 + 2 * q + 1];
  }
  inv_colrow(X, U, Ca0, Ca1);

  // ---------- accumulate into shared num/den tiles ---------------------------
#pragma unroll
  for (int r = 0; r < 2; r++)
#pragma unroll
    for (int c = 0; c < 8; c++) {
      int off = (gi + r) * TS + gj + c;
      atomicAdd(&accN[off], w * X[r][c]);
      atomicAdd(&accD[off], w);
    }
}

template <int WIEN>
__global__ __launch_bounds__(256, 5) void bm3d_pass(
    const int* __restrict__ img, const float* __restrict__ basic,
    const int* __restrict__ pvar,
    float* __restrict__ num, float* __restrict__ den) {
  __shared__ float ldsD[64];
  __shared__ int   ldsSel[4][16];
  __shared__ __align__(16) float wdist[4][84];
  __shared__ float tileN[32 * TS];
  __shared__ float tileB[WIEN ? 32 * TS : 1];
  __shared__ float accN[32 * TS], accD[32 * TS];

  int t = threadIdx.x;
  int brow = blockIdx.x / 24, bcb = blockIdx.x - brow * 24;
  int ri = brow * 4;
  int bim = ri - 12;      int bi = bim < 0 ? 0 : (bim > 352 ? 352 : bim);
  int ubm = 16 * bcb - 12; int ub = ubm < 0 ? 0 : (ubm > 352 ? 352 : ubm);

  if (t < 64) ldsD[t] = DCT8[t >> 3][t & 7];
  for (int e = t; e < 32 * 44; e += 256) {
    int r = e / 44, c = e - r * 44;
    int col = ub + c;
    bool ok = col < 384;
    tileN[r * TS + c] = ok ? (float)img[(bi + r) * 384 + col] : 0.f;
    if (WIEN) tileB[r * TS + c] = ok ? basic[(bi + r) * 384 + col] : 0.f;
  }
  for (int e = t; e < 32 * TS; e += 256) { accN[e] = 0.f; accD[e] = 0.f; }
  __syncthreads();

  float sigma2 = (float)pvar[0];
  int wv = t >> 6, lane = t & 63;
  int gc = bcb * 4 + wv;
  if (gc < 95) {
    group_worker<WIEN>(WIEN ? tileB : tileN, tileN, accN, accD, ldsD,
                       &ldsSel[wv][0], &wdist[wv][0],
                       lane, ri, gc * 4, bi, ub, sigma2);
  }
  __syncthreads();

  for (int e = t; e < 32 * TS; e += 256) {
    float dv = accD[e];
    if (dv != 0.f) {
      int r = e / TS, c = e - r * TS;
      int gp = (bi + r) * 384 + ub + c;
      atomicAdd(&num[gp], accN[e]);
      atomicAdd(&den[gp], dv);
    }
  }
}

__global__ void div_kernel(const float* __restrict__ num,
                           const float* __restrict__ den,
                           float* __restrict__ out, int npix) {
  int i = blockIdx.x * blockDim.x + threadIdx.x;
  if (i < npix) out[i] = num[i] / fmaxf(den[i], 1e-8f);
}

extern "C" void kernel_launch(void* const* d_in, const int* in_sizes, int n_in,
                              void* d_out, int out_size, void* d_ws, size_t ws_size,
                              hipStream_t stream) {
  const int* img  = (const int*)d_in[0];
  const int* pvar = (const int*)d_in[1];
  float* out = (float*)d_out;
  float* ws  = (float*)d_ws;

  const int NPIX = 384 * 384;
  float* num1  = ws + 0 * NPIX;
  float* den1  = ws + 1 * NPIX;
  float* basic = ws + 2 * NPIX;
  float* num2  = ws + 3 * NPIX;
  float* den2  = ws + 4 * NPIX;

  hipMemsetAsync(num1, 0, (size_t)2 * NPIX * sizeof(float), stream);
  hipMemsetAsync(num2, 0, (size_t)2 * NPIX * sizeof(float), stream);

  const int NBLK = 95 * 24;   // 95 rows x 24 col-blocks (4 groups each)
  bm3d_pass<0><<<NBLK, 256, 0, stream>>>(img, nullptr, pvar, num1, den1);
  div_kernel<<<(NPIX + 255) / 256, 256, 0, stream>>>(num1, den1, basic, NPIX);
  bm3d_pass<1><<<NBLK, 256, 0, stream>>>(img, basic, pvar, num2, den2);
  div_kernel<<<(NPIX + 255) / 256, 256, 0, stream>>>(num2, den2, out, NPIX);
}

// Round 12
// 273.527 us; speedup vs baseline: 1.4319x; 1.0123x over previous
//
#include <hip/hip_runtime.h>
#include <math.h>

#define TS 45            // LDS tile stride (32 rows x 44 used cols, +1 pad)
#define FINF 3.4e38f

__device__ __forceinline__ int iclip(int v, int hi) {
  return v < 0 ? 0 : (v > hi ? hi : v);
}

// Exact f32 values of the reference D8 (computed in f64, cast to f32).
constexpr float CA = 0.35355339059327373f;
constexpr float K1 = 0.49039264020161522f;
constexpr float K2 = 0.46193976625564337f;
constexpr float K3 = 0.41573480615127262f;
constexpr float K4 = 0.35355339059327379f;
constexpr float K5 = 0.27778511650980111f;
constexpr float K6 = 0.19134171618254489f;
constexpr float K7 = 0.097545161008064135f;

constexpr float DCT8[8][8] = {
  { CA, CA, CA, CA, CA, CA, CA, CA},
  { K1, K3, K5, K7,-K7,-K5,-K3,-K1},
  { K2, K6,-K6,-K2,-K2,-K6, K6, K2},
  { K3,-K7,-K1,-K5, K5, K1, K7,-K3},
  { K4,-K4,-K4, K4, K4,-K4,-K4, K4},
  { K5,-K1, K7, K3,-K3,-K7, K1,-K5},
  { K6,-K2, K2,-K6,-K6, K2,-K2, K6},
  { K7,-K5, K3,-K1, K1,-K3, K5,-K7},
};

// lane-xor exchange: DPP for 1/2, ds_swizzle for 4/8/16, shfl for 32
__device__ __forceinline__ int sxor_i(int v, int m) {
  switch (m) {
    case 1:  return __builtin_amdgcn_update_dpp(0, v, 0xB1, 0xF, 0xF, true); // quad_perm [1,0,3,2]
    case 2:  return __builtin_amdgcn_update_dpp(0, v, 0x4E, 0xF, 0xF, true); // quad_perm [2,3,0,1]
    case 4:  return __builtin_amdgcn_ds_swizzle(v, (4 << 10) | 0x1F);
    case 8:  return __builtin_amdgcn_ds_swizzle(v, (8 << 10) | 0x1F);
    case 16: return __builtin_amdgcn_ds_swizzle(v, (16 << 10) | 0x1F);
    default: return __shfl_xor(v, 32, 64);
  }
}
__device__ __forceinline__ float sxor_f(float v, int m) {
  return __int_as_float(sxor_i(__float_as_int(v), m));
}

// broadcast from quad lane s (VALU DPP, no LDS pipe)
__device__ __forceinline__ float qbcast(float v, int s) {
  int x = __float_as_int(v), r;
  switch (s) {
    case 0:  r = __builtin_amdgcn_update_dpp(0, x, 0x00, 0xF, 0xF, true); break;
    case 1:  r = __builtin_amdgcn_update_dpp(0, x, 0x55, 0xF, 0xF, true); break;
    case 2:  r = __builtin_amdgcn_update_dpp(0, x, 0xAA, 0xF, 0xF, true); break;
    default: r = __builtin_amdgcn_update_dpp(0, x, 0xFF, 0xF, 0xF, true); break;
  }
  return __int_as_float(r);
}

// forward: row DCT (lane-local, literal coeffs) then column DCT (quad mix)
__device__ __forceinline__ void fwd_rowcol(float X[2][8], float U[2][8],
                                           const float Ca0[8], const float Ca1[8]) {
#pragma unroll
  for (int r = 0; r < 2; r++)
#pragma unroll
    for (int d = 0; d < 8; d++) {
      float s = X[r][0] * DCT8[d][0];
#pragma unroll
      for (int c = 1; c < 8; c++) s += X[r][c] * DCT8[d][c];
      U[r][d] = s;
    }
#pragma unroll
  for (int r = 0; r < 2; r++)
#pragma unroll
    for (int d = 0; d < 8; d++) X[r][d] = 0.f;
#pragma unroll
  for (int b = 0; b < 8; b++)
#pragma unroll
    for (int d = 0; d < 8; d++) {
      float yb = qbcast(U[b & 1][d], b >> 1);
      X[0][d] += Ca0[b] * yb;
      X[1][d] += Ca1[b] * yb;
    }
}

// inverse: column (quad mix, D^T coeffs) then row (lane-local literals)
__device__ __forceinline__ void inv_colrow(float X[2][8], float U[2][8],
                                           const float Ct0[8], const float Ct1[8]) {
#pragma unroll
  for (int r = 0; r < 2; r++)
#pragma unroll
    for (int d = 0; d < 8; d++) U[r][d] = 0.f;
#pragma unroll
  for (int a = 0; a < 8; a++)
#pragma unroll
    for (int d = 0; d < 8; d++) {
      float za = qbcast(X[a & 1][d], a >> 1);
      U[0][d] += Ct0[a] * za;
      U[1][d] += Ct1[a] * za;
    }
#pragma unroll
  for (int r = 0; r < 2; r++)
#pragma unroll
    for (int c = 0; c < 8; c++) {
      float s = U[r][0] * DCT8[0][c];
#pragma unroll
      for (int d = 1; d < 8; d++) s += U[r][d] * DCT8[d][c];
      X[r][c] = s;
    }
}

// 16-point Walsh-Hadamard across lane bits 2..5 (k dim), scale 1/4
__device__ __forceinline__ void had16r(float X[2][8], int lane) {
#pragma unroll
  for (int m = 4; m <= 32; m <<= 1) {
    bool hi = (lane & m) != 0;
#pragma unroll
    for (int r = 0; r < 2; r++)
#pragma unroll
      for (int d = 0; d < 8; d++) {
        float tv = sxor_f(X[r][d], m);
        X[r][d] = hi ? (tv - X[r][d]) : (X[r][d] + tv);
      }
  }
#pragma unroll
  for (int r = 0; r < 2; r++)
#pragma unroll
    for (int d = 0; d < 8; d++) X[r][d] *= 0.25f;
}

template <int WIEN>
__device__ __forceinline__ void group_worker(
    const float* __restrict__ tileS, const float* __restrict__ tileN,
    float* __restrict__ accN, float* __restrict__ accD,
    const float* __restrict__ ldsD, int* __restrict__ sel,
    float* __restrict__ wdrow,
    int lane, int ri, int rj, int bi, int ub, float sigma2) {

  // ---------- block match: 81 candidates, lane holds cand lane and 64+lane ----
  int cB = lane < 17 ? 64 + lane : 80;
  int aiA = iclip(ri + (lane / 9) * 3 - 12, 376) - bi;
  int ajA = iclip(rj + (lane % 9) * 3 - 12, 376) - ub;
  int aiB = iclip(ri + (cB / 9) * 3 - 12, 376) - bi;
  int ajB = iclip(rj + (cB % 9) * 3 - 12, 376) - ub;
  int roi = ri - bi, roj = rj - ub;
  float sccA = 0.f, scrA = 0.f, sccB = 0.f, scrB = 0.f, srr = 0.f;
#pragma unroll
  for (int i = 0; i < 8; i++) {
    const float* rr = tileS + (roi + i) * TS + roj;
    const float* ar = tileS + (aiA + i) * TS + ajA;
    const float* br = tileS + (aiB + i) * TS + ajB;
#pragma unroll
    for (int j = 0; j < 8; j++) {
      float rv = rr[j], av = ar[j], bv = br[j];
      sccA += av * av; scrA += av * rv;
      sccB += bv * bv; scrB += bv * rv;
      srr  += rv * rv;
    }
  }
  float d0 = sccA - 2.f * scrA + srr;
  float d1 = lane < 17 ? (sccB - 2.f * scrB + srr) : FINF;

  // ---------- rank-count top-16 (lexicographic (d, idx) = lax.top_k order) ----
  // per-wave dist table; same-wave LDS RAW (compiler inserts lgkm waits)
  wdrow[lane] = d0;
  if (lane < 17)      wdrow[64 + lane] = d1;
  else if (lane < 20) wdrow[64 + lane] = FINF;

  int rank0 = 0, rank1 = 0;
  const float4* wp = (const float4*)wdrow;
  int idxB = 64 + lane;
#pragma unroll 3
  for (int c4 = 0; c4 < 21; c4++) {
    float4 v = wp[c4];
    float ev[4] = {v.x, v.y, v.z, v.w};
#pragma unroll
    for (int u = 0; u < 4; u++) {
      int c2 = c4 * 4 + u;
      rank0 += (ev[u] < d0 || (ev[u] == d0 && c2 < lane)) ? 1 : 0;
      rank1 += (ev[u] < d1 || (ev[u] == d1 && c2 < idxB)) ? 1 : 0;
    }
  }
  if (rank0 < 16) sel[rank0] = (aiA << 8) | ajA;
  if (lane < 17 && rank1 < 16) sel[rank1] = (aiB << 8) | ajB;

  // ---------- per-lane geometry + column-DCT coefficient rows ---------------
  int q = lane & 3, k = lane >> 2;
  float Ca0[8], Ca1[8];
#pragma unroll
  for (int b = 0; b < 8; b++) {
    Ca0[b] = ldsD[(2 * q) * 8 + b];
    Ca1[b] = ldsD[(2 * q + 1) * 8 + b];
  }
  int sp = sel[k];
  int gi = (sp >> 8) + 2 * q, gj = sp & 255;

  float X[2][8], U[2][8], ZB[2][8];
  float w;

  if (WIEN) {                      // cb = fwd3d(basic group)
#pragma unroll
    for (int r = 0; r < 2; r++)
#pragma unroll
      for (int c = 0; c < 8; c++) ZB[r][c] = tileS[(gi + r) * TS + gj + c];
    fwd_rowcol(ZB, U, Ca0, Ca1);
    had16r(ZB, lane);
  }

  // cn / noisy group
#pragma unroll
  for (int r = 0; r < 2; r++)
#pragma unroll
    for (int c = 0; c < 8; c++) X[r][c] = tileN[(gi + r) * TS + gj + c];
  fwd_rowcol(X, U, Ca0, Ca1);
  had16r(X, lane);

  if (WIEN) {
    float part = 0.f;
#pragma unroll
    for (int r = 0; r < 2; r++)
#pragma unroll
      for (int d = 0; d < 8; d++) {
        float cb = ZB[r][d];
        float we = cb * cb / (cb * cb + sigma2);
        X[r][d] = we * X[r][d];
        part += we * we;
      }
#pragma unroll
    for (int m = 1; m <= 32; m <<= 1) part += sxor_f(part, m);
    w = 1.f / (sigma2 * fmaxf(part, 1e-8f));
  } else {
    float thr = 2.7f * sqrtf(sigma2);
    int cnt = 0;
#pragma unroll
    for (int r = 0; r < 2; r++)
#pragma unroll
      for (int d = 0; d < 8; d++) {
        bool keep = (fabsf(X[r][d]) > thr) || (lane == 0 && r == 0 && d == 0);
        cnt += (int)__popcll(__ballot(keep));
        if (!keep) X[r][d] = 0.f;
      }
    w = 1.f / (sigma2 * fmaxf((float)cnt, 1.f));
  }

  // ---------- inverse 3D transform ------------------------------------------
  had16r(X, lane);
#pragma unroll
  for (int a = 0; a < 8; a++) {    // D^T rows for this lane's two b's
    Ca0[a] = ldsD[a * 8 + 2 * q];
    Ca1[a] = ldsD[a * 8 + 2 * q + 1];
  }
  inv_colrow(X, U, Ca0, Ca1);

  // ---------- accumulate into shared num/den tiles ---------------------------
#pragma unroll
  for (int r = 0; r < 2; r++)
#pragma unroll
    for (int c = 0; c < 8; c++) {
      int off = (gi + r) * TS + gj + c;
      atomicAdd(&accN[off], w * X[r][c]);
      atomicAdd(&accD[off], w);
    }
}

// WIEN=0: match source = img (int). WIEN=1: match source = num1/den1 (basic).
template <int WIEN>
__global__ __launch_bounds__(256, 6) void bm3d_pass(
    const int* __restrict__ img,
    const float* __restrict__ bn, const float* __restrict__ bd,
    const int* __restrict__ pvar,
    float* __restrict__ num, float* __restrict__ den) {
  __shared__ float ldsD[64];
  __shared__ int   ldsSel[4][16];
  __shared__ __align__(16) float wdist[4][84];
  __shared__ float tileN[32 * TS];
  __shared__ float tileB[WIEN ? 32 * TS : 1];
  __shared__ float accN[32 * TS], accD[32 * TS];

  int t = threadIdx.x;
  int brow = blockIdx.x / 24, bcb = blockIdx.x - brow * 24;
  int ri = brow * 4;
  int bim = ri - 12;      int bi = bim < 0 ? 0 : (bim > 352 ? 352 : bim);
  int ubm = 16 * bcb - 12; int ub = ubm < 0 ? 0 : (ubm > 352 ? 352 : ubm);

  if (t < 64) ldsD[t] = DCT8[t >> 3][t & 7];
  for (int e = t; e < 32 * 44; e += 256) {
    int r = e / 44, c = e - r * 44;
    int col = ub + c;
    bool ok = col < 384;
    int gidx = (bi + r) * 384 + col;
    tileN[r * TS + c] = ok ? (float)img[gidx] : 0.f;
    if (WIEN)  // basic = num1 / max(den1, 1e-8), same expr as old div kernel
      tileB[r * TS + c] = ok ? (bn[gidx] / fmaxf(bd[gidx], 1e-8f)) : 0.f;
  }
  for (int e = t; e < 32 * TS; e += 256) { accN[e] = 0.f; accD[e] = 0.f; }
  __syncthreads();

  float sigma2 = (float)pvar[0];
  int wv = t >> 6, lane = t & 63;
  int gc = bcb * 4 + wv;
  if (gc < 95) {
    group_worker<WIEN>(WIEN ? tileB : tileN, tileN, accN, accD, ldsD,
                       &ldsSel[wv][0], &wdist[wv][0],
                       lane, ri, gc * 4, bi, ub, sigma2);
  }
  __syncthreads();

  for (int e = t; e < 32 * TS; e += 256) {
    float dv = accD[e];
    if (dv != 0.f) {
      int r = e / TS, c = e - r * TS;
      int gp = (bi + r) * 384 + ub + c;
      atomicAdd(&num[gp], accN[e]);
      atomicAdd(&den[gp], dv);
    }
  }
}

__global__ void div_kernel(const float* __restrict__ num,
                           const float* __restrict__ den,
                           float* __restrict__ out, int npix) {
  int i = blockIdx.x * blockDim.x + threadIdx.x;
  if (i < npix) out[i] = num[i] / fmaxf(den[i], 1e-8f);
}

extern "C" void kernel_launch(void* const* d_in, const int* in_sizes, int n_in,
                              void* d_out, int out_size, void* d_ws, size_t ws_size,
                              hipStream_t stream) {
  const int* img  = (const int*)d_in[0];
  const int* pvar = (const int*)d_in[1];
  float* out = (float*)d_out;
  float* ws  = (float*)d_ws;

  const int NPIX = 384 * 384;
  float* num1 = ws + 0 * NPIX;
  float* den1 = ws + 1 * NPIX;
  float* num2 = ws + 2 * NPIX;
  float* den2 = ws + 3 * NPIX;

  // single memset over contiguous num1|den1|num2|den2
  hipMemsetAsync(num1, 0, (size_t)4 * NPIX * sizeof(float), stream);

  const int NBLK = 95 * 24;   // 95 rows x 24 col-blocks (4 groups each)
  bm3d_pass<0><<<NBLK, 256, 0, stream>>>(img, nullptr, nullptr, pvar, num1, den1);
  bm3d_pass<1><<<NBLK, 256, 0, stream>>>(img, num1, den1, pvar, num2, den2);
  div_kernel<<<(NPIX + 255) / 256, 256, 0, stream>>>(num2, den2, out, NPIX);
}